// Round 13
// baseline (133.499 us; speedup 1.0000x reference)
//
#include <hip/hip_runtime.h>
#include <hip/hip_bf16.h>

// B=8, F=4, T=S=1024, C=32, C2=64, NH=2, HD=16
// Inputs fp32, output fp32. k/v staged bf16 in ws; q stays in LDS (fused).
#define T_LEN 1024

typedef __attribute__((ext_vector_type(8))) short short8;   // 8 bf16 = 4 VGPR
typedef __attribute__((ext_vector_type(4))) short short4v;
typedef __attribute__((ext_vector_type(4))) float float4v;

__device__ __forceinline__ float gelu_exact(float x) {
    return 0.5f * x * (1.0f + erff(x * 0.70710678118654752440f));
}
__device__ __forceinline__ unsigned short f2bf(float f) {   // RNE
    unsigned u = __float_as_uint(f);
    u += 0x7fffu + ((u >> 16) & 1u);
    return (unsigned short)(u >> 16);
}
__device__ __forceinline__ unsigned pk2bf(float a, float b) {  // (lo=a, hi=b)
    __hip_bfloat162 h = __float22bfloat162_rn(make_float2(a, b));
    unsigned u;
    __builtin_memcpy(&u, &h, 4);
    return u;
}

// ---------------------------------------------------------------------------
// kv_tcl: k/v TCL (R10-proven), 512 blocks x 256 thr, 32-row tiles.
// [0,256): k -> kbf [8][1024][32]; [256,512): v -> vtbf [8][2][16][1024].
// ---------------------------------------------------------------------------
__global__ __launch_bounds__(256) void kv_tcl(
    const float* __restrict__ pkv,
    const float* __restrict__ wkc, const float* __restrict__ bkc,
    const float* __restrict__ wkp, const float* __restrict__ bkp,
    const float* __restrict__ wvc, const float* __restrict__ bvc,
    const float* __restrict__ wvp, const float* __restrict__ bvp,
    unsigned short* __restrict__ kbf, unsigned short* __restrict__ vtbf)
{
    __shared__ __align__(16) unsigned short Abuf[32 * 96];
    __shared__ __align__(16) unsigned short WbT[64 * 96];
    __shared__ __align__(16) unsigned short Hb[32 * 72];
    __shared__ __align__(16) unsigned short WpB[32 * 72];

    const int tid = threadIdx.x;
    const int gb = blockIdx.x;

    const float *wc, *bc, *wp, *bp;
    unsigned short* outb;
    int n, mode;
    if (gb < 256) { n = gb >> 5;         wc = wkc; bc = bkc; wp = wkp; bp = bkp; outb = kbf;  mode = 0; }
    else          { n = (gb - 256) >> 5; wc = wvc; bc = bvc; wp = wvp; bp = bvp; outb = vtbf; mode = 1; }
    const int t0 = (gb & 31) * 32;

#pragma unroll
    for (int it = 0; it < 3; ++it) {
        int s = (tid + it * 256) >> 3;
        int sub = tid & 7;
        int t = s / 3, tap = s - t * 3;
        int tau = t0 + t - 2 + tap;
        float4 xv = make_float4(0.f, 0.f, 0.f, 0.f);
        if (tau >= 0) xv = *(const float4*)&pkv[((size_t)n * T_LEN + tau) * 32 + sub * 4];
        short4v pk = { (short)f2bf(xv.x), (short)f2bf(xv.y),
                       (short)f2bf(xv.z), (short)f2bf(xv.w) };
        *(short4v*)&Abuf[t * 96 + tap * 32 + sub * 4] = pk;
    }
#pragma unroll
    for (int it = 0; it < 6; ++it) {
        int i4 = tid + it * 256;
        int idx = i4 * 4;
        int o = idx / 96, r = idx - o * 96;
        float4 w4 = *(const float4*)&wc[idx];
        float we[4] = { w4.x, w4.y, w4.z, w4.w };
#pragma unroll
        for (int e = 0; e < 4; ++e) {
            int re = r + e, c = re / 3, tap = re - c * 3;
            WbT[o * 96 + tap * 32 + c] = f2bf(we[e]);
        }
    }
#pragma unroll
    for (int it = 0; it < 2; ++it) {
        int i4 = tid + it * 256;
        int idx = i4 * 4;
        int c = idx >> 6, o = idx & 63;
        float4 w4 = *(const float4*)&wp[idx];
        short4v pk = { (short)f2bf(w4.x), (short)f2bf(w4.y),
                       (short)f2bf(w4.z), (short)f2bf(w4.w) };
        *(short4v*)&WpB[c * 72 + o] = pk;
    }

    const int w = tid >> 6;
    const int ln = tid & 63;
    const int sn = ln & 15;
    const int quad = ln >> 4;

    const float bcv = bc[w * 16 + sn];
    const int tmw = w & 1, cnw = w >> 1;
    const float bpv = bp[cnw * 16 + sn];

    __syncthreads();

    short8 b0 = *(const short8*)&WbT[(w * 16 + sn) * 96 + 0  + quad * 8];
    short8 b1 = *(const short8*)&WbT[(w * 16 + sn) * 96 + 32 + quad * 8];
    short8 b2 = *(const short8*)&WbT[(w * 16 + sn) * 96 + 64 + quad * 8];
    float4v zero = { 0.f, 0.f, 0.f, 0.f };
    float4v acc[2] = { zero, zero };
#pragma unroll
    for (int tm = 0; tm < 2; ++tm) {
        const unsigned short* ar = &Abuf[(tm * 16 + sn) * 96 + quad * 8];
        short8 a0 = *(const short8*)(ar + 0);
        short8 a1 = *(const short8*)(ar + 32);
        short8 a2 = *(const short8*)(ar + 64);
        acc[tm] = __builtin_amdgcn_mfma_f32_16x16x32_bf16(a0, b0, acc[tm], 0, 0, 0);
        acc[tm] = __builtin_amdgcn_mfma_f32_16x16x32_bf16(a1, b1, acc[tm], 0, 0, 0);
        acc[tm] = __builtin_amdgcn_mfma_f32_16x16x32_bf16(a2, b2, acc[tm], 0, 0, 0);
    }
#pragma unroll
    for (int tm = 0; tm < 2; ++tm) {
        float ge[4];
        ge[0] = gelu_exact(acc[tm].x + bcv);
        ge[1] = gelu_exact(acc[tm].y + bcv);
        ge[2] = gelu_exact(acc[tm].z + bcv);
        ge[3] = gelu_exact(acc[tm].w + bcv);
#pragma unroll
        for (int i = 0; i < 4; ++i)
            Hb[(tm * 16 + quad * 4 + i) * 72 + w * 16 + sn] = f2bf(ge[i]);
    }

    __syncthreads();

    const unsigned short* hr = &Hb[(tmw * 16 + sn) * 72 + quad * 8];
    short8 pa0 = *(const short8*)(hr + 0);
    short8 pa1 = *(const short8*)(hr + 32);
    short8 pb0 = *(const short8*)&WpB[(cnw * 16 + sn) * 72 + quad * 8];
    short8 pb1 = *(const short8*)&WpB[(cnw * 16 + sn) * 72 + 32 + quad * 8];
    float4v pacc = zero;
    pacc = __builtin_amdgcn_mfma_f32_16x16x32_bf16(pa0, pb0, pacc, 0, 0, 0);
    pacc = __builtin_amdgcn_mfma_f32_16x16x32_bf16(pa1, pb1, pacc, 0, 0, 0);

    float v[4] = { pacc.x + bpv, pacc.y + bpv, pacc.z + bpv, pacc.w + bpv };
#pragma unroll
    for (int i = 0; i < 4; ++i) {
        int t = tmw * 16 + quad * 4 + i;
        int c = cnw * 16 + sn;
        if (mode == 0) {
            outb[((size_t)n * T_LEN + t0 + t) * 32 + c] = f2bf(v[i]);
        } else {
            outb[((size_t)(n * 2 + cnw) * 16 + sn) * T_LEN + t0 + t] = f2bf(v[i]);
        }
    }
}

// ---------------------------------------------------------------------------
// fused_qae v2: 1024 blocks x 512 thr (4 blocks/CU -> 32 waves/CU; R12's 512
// blocks capped at 2/CU). Per (bf, 32-row t-tile): q-TCL -> LDS, attention
// (8 waves = 2 row-tiles x 2 heads x 2 S-halves, dual-stream; S-half partials
// merged in LDS), epilogue (2 passes of 16 rows).
// LDS overlay, 30208 B total:
//   A: Abuf[0,6144) WbT[6144,18432) Hb[18432,23040) WpB[23040,27648)
//   persistent: qs[27648,30208) (pitch 40 shorts, SC-prescaled q)
//   B: plds[0,18432) overlays Abuf/WbT; pbuf[18432,22528) lbuf[22528,22784)
//      sy[22784,26880) overlay dead Hb/WpB
//   C (plds dead after merge barrier): swc@0 swf@4608 swm@9216 sln@13824
//      shn@13952 sg@16256
// ---------------------------------------------------------------------------
__global__ __launch_bounds__(512) void fused_qae(
    const float* __restrict__ cd,
    const float* __restrict__ wqc, const float* __restrict__ bqc,
    const float* __restrict__ wqp, const float* __restrict__ bqp,
    const unsigned short* __restrict__ kbf,
    const unsigned short* __restrict__ vtbf,
    const float* __restrict__ wcp, const float* __restrict__ lnw,
    const float* __restrict__ wfc, const float* __restrict__ wmp,
    float* __restrict__ out)
{
    __shared__ __align__(16) char smem[30208];
    unsigned short* Abuf = (unsigned short*)(smem);
    unsigned short* WbT  = (unsigned short*)(smem + 6144);
    unsigned short* Hb   = (unsigned short*)(smem + 18432);
    unsigned short* WpB  = (unsigned short*)(smem + 23040);
    unsigned short* qs   = (unsigned short*)(smem + 27648);
    unsigned short* plds = (unsigned short*)(smem);          // phase B overlay

    const int tid = threadIdx.x;
    const int bf = blockIdx.x >> 5;
    const int tt = blockIdx.x & 31;
    const int t0 = tt * 32;
    const int b = bf >> 2;
    const float SC = 0.36067376022224085f;    // 0.25 * log2(e)

    // ---- phase A staging
#pragma unroll
    for (int it = 0; it < 2; ++it) {
        int idx = tid + it * 512;             // 0..1023, need 768
        if (idx < 768) {
            int s = idx >> 3;                 // 0..95
            int sub = idx & 7;
            int t = s / 3, tap = s - t * 3;
            int tau = t0 + t - 2 + tap;
            float4 xv = make_float4(0.f, 0.f, 0.f, 0.f);
            if (tau >= 0) xv = *(const float4*)&cd[((size_t)bf * T_LEN + tau) * 32 + sub * 4];
            short4v pk = { (short)f2bf(xv.x), (short)f2bf(xv.y),
                           (short)f2bf(xv.z), (short)f2bf(xv.w) };
            *(short4v*)&Abuf[t * 96 + tap * 32 + sub * 4] = pk;
        }
    }
#pragma unroll
    for (int it = 0; it < 3; ++it) {
        int i4 = tid + it * 512;              // 0..1535
        int idx = i4 * 4;
        int o = idx / 96, r = idx - o * 96;
        float4 w4 = *(const float4*)&wqc[idx];
        float we[4] = { w4.x, w4.y, w4.z, w4.w };
#pragma unroll
        for (int e = 0; e < 4; ++e) {
            int re = r + e, c = re / 3, tap = re - c * 3;
            WbT[o * 96 + tap * 32 + c] = f2bf(we[e]);
        }
    }
    {
        int idx = tid * 4;                    // 512 float4s
        int c = idx >> 6, o = idx & 63;
        float4 w4 = *(const float4*)&wqp[idx];
        short4v pk = { (short)f2bf(w4.x), (short)f2bf(w4.y),
                       (short)f2bf(w4.z), (short)f2bf(w4.w) };
        *(short4v*)&WpB[c * 72 + o] = pk;
    }

    const int w = tid >> 6;       // wave 0..7
    const int ln = tid & 63;
    const int sn = ln & 15;
    const int quad = ln >> 4;
    const float4v zero = { 0.f, 0.f, 0.f, 0.f };

    __syncthreads();

    // ---- phase A conv GEMM: wave w -> t-tile w&1, o-tile w>>1 (3 MFMAs)
    {
        const int tm = w & 1, on = w >> 1;
        const unsigned short* ar = &Abuf[(tm * 16 + sn) * 96 + quad * 8];
        short8 a0 = *(const short8*)(ar + 0);
        short8 a1 = *(const short8*)(ar + 32);
        short8 a2 = *(const short8*)(ar + 64);
        const unsigned short* br = &WbT[(on * 16 + sn) * 96 + quad * 8];
        float4v c0 = zero;
        c0 = __builtin_amdgcn_mfma_f32_16x16x32_bf16(a0, *(const short8*)(br + 0),  c0, 0, 0, 0);
        c0 = __builtin_amdgcn_mfma_f32_16x16x32_bf16(a1, *(const short8*)(br + 32), c0, 0, 0, 0);
        c0 = __builtin_amdgcn_mfma_f32_16x16x32_bf16(a2, *(const short8*)(br + 64), c0, 0, 0, 0);
        const float bc0 = bqc[on * 16 + sn];
        float g0[4] = { gelu_exact(c0.x + bc0), gelu_exact(c0.y + bc0),
                        gelu_exact(c0.z + bc0), gelu_exact(c0.w + bc0) };
#pragma unroll
        for (int i = 0; i < 4; ++i)
            Hb[(tm * 16 + quad * 4 + i) * 72 + on * 16 + sn] = f2bf(g0[i]);
    }
    __syncthreads();

    // ---- phase A proj GEMM (waves 0-3) -> qs (pre-scaled by SC)
    if (w < 4) {
        const int tm = w & 1, cn = w >> 1;
        const unsigned short* hr = &Hb[(tm * 16 + sn) * 72 + quad * 8];
        short8 pa0 = *(const short8*)(hr + 0);
        short8 pa1 = *(const short8*)(hr + 32);
        const unsigned short* wr_ = &WpB[(cn * 16 + sn) * 72 + quad * 8];
        short8 pb0 = *(const short8*)(wr_ + 0);
        short8 pb1 = *(const short8*)(wr_ + 32);
        float4v pacc = zero;
        pacc = __builtin_amdgcn_mfma_f32_16x16x32_bf16(pa0, pb0, pacc, 0, 0, 0);
        pacc = __builtin_amdgcn_mfma_f32_16x16x32_bf16(pa1, pb1, pacc, 0, 0, 0);
        const float bpv = bqp[cn * 16 + sn];
        float v[4] = { (pacc.x + bpv) * SC, (pacc.y + bpv) * SC,
                       (pacc.z + bpv) * SC, (pacc.w + bpv) * SC };
#pragma unroll
        for (int i = 0; i < 4; ++i)
            qs[(tm * 16 + quad * 4 + i) * 40 + cn * 16 + sn] = f2bf(v[i]);
    }
    __syncthreads();

    // ---- phase B attention: wave w -> h=w&1, rt=(w>>1)&1, s-half sh=w>>2
    const int h = w & 1, rt = (w >> 1) & 1, sh = w >> 2;
    short8 aq = {0, 0, 0, 0, 0, 0, 0, 0};
    if (quad < 2)
        aq = *(const short8*)&qs[(rt * 16 + sn) * 40 + h * 16 + quad * 8];

    const unsigned short* kb = kbf + (size_t)b * T_LEN * 32 + h * 16 + quad * 8;
    const unsigned short* vb = vtbf + ((size_t)(b * 2 + h) * 16 + sn) * T_LEN + quad * 8;
    unsigned short* pwA = plds + w * 1152;
    unsigned short* pwB = pwA + 576;

    float4v yacc = zero;
    float l0 = 0.f, l1 = 0.f, l2 = 0.f, l3 = 0.f;
    const int sbeg = sh * 512;

#pragma unroll 1
    for (int s0 = sbeg; s0 < sbeg + 512; s0 += 64) {
        short8 ka0 = {0,0,0,0,0,0,0,0}, ka1 = ka0, kb0 = ka0, kb1 = ka0;
        if (quad < 2) {
            ka0 = *(const short8*)(kb + (size_t)(s0 + sn) * 32);
            ka1 = *(const short8*)(kb + (size_t)(s0 + 16 + sn) * 32);
            kb0 = *(const short8*)(kb + (size_t)(s0 + 32 + sn) * 32);
            kb1 = *(const short8*)(kb + (size_t)(s0 + 48 + sn) * 32);
        }
        short8 bvA = *(const short8*)(vb + s0);
        short8 bvB = *(const short8*)(vb + s0 + 32);

        float4v cA0 = __builtin_amdgcn_mfma_f32_16x16x32_bf16(aq, ka0, zero, 0, 0, 0);
        float4v cA1 = __builtin_amdgcn_mfma_f32_16x16x32_bf16(aq, ka1, zero, 0, 0, 0);
        float4v cB0 = __builtin_amdgcn_mfma_f32_16x16x32_bf16(aq, kb0, zero, 0, 0, 0);
        float4v cB1 = __builtin_amdgcn_mfma_f32_16x16x32_bf16(aq, kb1, zero, 0, 0, 0);

        float a0x = exp2f(cA0.x), a0y = exp2f(cA0.y), a0z = exp2f(cA0.z), a0w = exp2f(cA0.w);
        float a1x = exp2f(cA1.x), a1y = exp2f(cA1.y), a1z = exp2f(cA1.z), a1w = exp2f(cA1.w);
        float b0x = exp2f(cB0.x), b0y = exp2f(cB0.y), b0z = exp2f(cB0.z), b0w = exp2f(cB0.w);
        float b1x = exp2f(cB1.x), b1y = exp2f(cB1.y), b1z = exp2f(cB1.z), b1w = exp2f(cB1.w);

        l0 += (a0x + a1x) + (b0x + b1x);
        l1 += (a0y + a1y) + (b0y + b1y);
        l2 += (a0z + a1z) + (b0z + b1z);
        l3 += (a0w + a1w) + (b0w + b1w);

        const int tb = quad * 4;
        unsigned uA0 = pk2bf(a0x, a1x), uA1 = pk2bf(a0y, a1y);
        unsigned uA2 = pk2bf(a0z, a1z), uA3 = pk2bf(a0w, a1w);
        unsigned uB0 = pk2bf(b0x, b1x), uB1 = pk2bf(b0y, b1y);
        unsigned uB2 = pk2bf(b0z, b1z), uB3 = pk2bf(b0w, b1w);
        pwA[(tb + 0) * 36 + sn]      = (unsigned short)uA0;
        pwA[(tb + 0) * 36 + 16 + sn] = (unsigned short)(uA0 >> 16);
        pwA[(tb + 1) * 36 + sn]      = (unsigned short)uA1;
        pwA[(tb + 1) * 36 + 16 + sn] = (unsigned short)(uA1 >> 16);
        pwA[(tb + 2) * 36 + sn]      = (unsigned short)uA2;
        pwA[(tb + 2) * 36 + 16 + sn] = (unsigned short)(uA2 >> 16);
        pwA[(tb + 3) * 36 + sn]      = (unsigned short)uA3;
        pwA[(tb + 3) * 36 + 16 + sn] = (unsigned short)(uA3 >> 16);
        pwB[(tb + 0) * 36 + sn]      = (unsigned short)uB0;
        pwB[(tb + 0) * 36 + 16 + sn] = (unsigned short)(uB0 >> 16);
        pwB[(tb + 1) * 36 + sn]      = (unsigned short)uB1;
        pwB[(tb + 1) * 36 + 16 + sn] = (unsigned short)(uB1 >> 16);
        pwB[(tb + 2) * 36 + sn]      = (unsigned short)uB2;
        pwB[(tb + 2) * 36 + 16 + sn] = (unsigned short)(uB2 >> 16);
        pwB[(tb + 3) * 36 + sn]      = (unsigned short)uB3;
        pwB[(tb + 3) * 36 + 16 + sn] = (unsigned short)(uB3 >> 16);

        const unsigned short* prA = pwA + sn * 36 + quad * 8;
        const unsigned short* prB = pwB + sn * 36 + quad * 8;
        short4v aloA = *(const short4v*)prA;
        short4v ahiA = *(const short4v*)(prA + 4);
        short4v aloB = *(const short4v*)prB;
        short4v ahiB = *(const short4v*)(prB + 4);
        short8 apA = {aloA.x, aloA.y, aloA.z, aloA.w, ahiA.x, ahiA.y, ahiA.z, ahiA.w};
        short8 apB = {aloB.x, aloB.y, aloB.z, aloB.w, ahiB.x, ahiB.y, ahiB.z, ahiB.w};

        yacc = __builtin_amdgcn_mfma_f32_16x16x32_bf16(apA, bvA, yacc, 0, 0, 0);
        yacc = __builtin_amdgcn_mfma_f32_16x16x32_bf16(apB, bvB, yacc, 0, 0, 0);
    }

#pragma unroll
    for (int off = 1; off < 16; off <<= 1) {
        l0 += __shfl_xor(l0, off); l1 += __shfl_xor(l1, off);
        l2 += __shfl_xor(l2, off); l3 += __shfl_xor(l3, off);
    }

    // ---- S-half merge: sh=1 deposits partials, sh=0 merges + writes sy
    float* pbuf = (float*)(smem + 18432);     // 4 x 1024 B (overlays dead Hb)
    float* lbuf = (float*)(smem + 22528);     // 4 x 16 floats
    float* sy   = (float*)(smem + 22784);     // [32][32] f32
    const int wj = w & 3;
    if (sh == 1) {
        *(float4*)(pbuf + wj * 256 + ln * 4) =
            make_float4(yacc.x, yacc.y, yacc.z, yacc.w);
        if (sn == 0) {
            lbuf[wj * 16 + quad * 4 + 0] = l0;
            lbuf[wj * 16 + quad * 4 + 1] = l1;
            lbuf[wj * 16 + quad * 4 + 2] = l2;
            lbuf[wj * 16 + quad * 4 + 3] = l3;
        }
    }
    __syncthreads();
    if (sh == 0) {
        float4 o = *(float4*)(pbuf + wj * 256 + ln * 4);
        yacc.x += o.x; yacc.y += o.y; yacc.z += o.z; yacc.w += o.w;
        l0 += lbuf[wj * 16 + quad * 4 + 0];
        l1 += lbuf[wj * 16 + quad * 4 + 1];
        l2 += lbuf[wj * 16 + quad * 4 + 2];
        l3 += lbuf[wj * 16 + quad * 4 + 3];
        const float i0 = 1.f / l0, i1 = 1.f / l1, i2 = 1.f / l2, i3 = 1.f / l3;
        const int r0 = rt * 16 + quad * 4;
        sy[(r0 + 0) * 32 + h * 16 + sn] = yacc.x * i0;
        sy[(r0 + 1) * 32 + h * 16 + sn] = yacc.y * i1;
        sy[(r0 + 2) * 32 + h * 16 + sn] = yacc.z * i2;
        sy[(r0 + 3) * 32 + h * 16 + sn] = yacc.w * i3;
    }

    // ---- phase C staging (overlays dead plds region, disjoint from pbuf/sy)
    float* swc = (float*)(smem + 0);          // [32][36]
    float* swf = (float*)(smem + 4608);
    float* swm = (float*)(smem + 9216);
    float* sln = (float*)(smem + 13824);
    float* shn = (float*)(smem + 13952);      // [16][36]
    float* sgv = (float*)(smem + 16256);
    for (int i = tid; i < 1024; i += 512) {
        int r = i >> 5, cc = i & 31;
        swc[r * 36 + cc] = wcp[i];
        swf[r * 36 + cc] = wfc[i];
        swm[r * 36 + cc] = wmp[i];
    }
    if (tid < 32) sln[tid] = lnw[tid];
    __syncthreads();

    const int rl = tid >> 5, c = tid & 31;
    const float lnwc = sln[c];
#pragma unroll 1
    for (int p = 0; p < 2; ++p) {
        int r = p * 16 + rl;
        size_t row = (size_t)bf * T_LEN + t0 + r;
        float x1 = cd[row * 32 + c];
#pragma unroll
        for (int j4 = 0; j4 < 8; ++j4) {
            float4 yv = *(const float4*)&sy[r * 32 + j4 * 4];
            const float* wv = &swc[c * 36 + j4 * 4];
            x1 += wv[0] * yv.x + wv[1] * yv.y + wv[2] * yv.z + wv[3] * yv.w;
        }
        float s1 = x1, s2 = x1 * x1;
#pragma unroll
        for (int off = 16; off; off >>= 1) {
            s1 += __shfl_xor(s1, off);
            s2 += __shfl_xor(s2, off);
        }
        float mu = s1 * (1.0f / 32.0f);
        float var = s2 * (1.0f / 32.0f) - mu * mu;
        float hn = (x1 - mu) * rsqrtf(var + 1e-5f) * lnwc;
        shn[rl * 36 + c] = hn;
        float ga = 0.f;
#pragma unroll
        for (int j4 = 0; j4 < 8; ++j4) {
            float4 hv = *(const float4*)&shn[rl * 36 + j4 * 4];
            const float* wv = &swf[c * 36 + j4 * 4];
            ga += wv[0] * hv.x + wv[1] * hv.y + wv[2] * hv.z + wv[3] * hv.w;
        }
        float gv = gelu_exact(ga);
        sgv[rl * 36 + c] = gv;
        float oa = x1;
#pragma unroll
        for (int j4 = 0; j4 < 8; ++j4) {
            float4 gvv = *(const float4*)&sgv[rl * 36 + j4 * 4];
            const float* wv = &swm[c * 36 + j4 * 4];
            oa += wv[0] * gvv.x + wv[1] * gvv.y + wv[2] * gvv.z + wv[3] * gvv.w;
        }
        out[row * 32 + c] = oa;
    }
}

// ---------------------------------------------------------------------------
extern "C" void kernel_launch(void* const* d_in, const int* in_sizes, int n_in,
                              void* d_out, int out_size, void* d_ws, size_t ws_size,
                              hipStream_t stream) {
    const float* cd  = (const float*)d_in[0];
    const float* pkv = (const float*)d_in[1];
    const float* wqc = (const float*)d_in[2];
    const float* bqc = (const float*)d_in[3];
    const float* wqp = (const float*)d_in[4];
    const float* bqp = (const float*)d_in[5];
    const float* wkc = (const float*)d_in[6];
    const float* bkc = (const float*)d_in[7];
    const float* wkp = (const float*)d_in[8];
    const float* bkp = (const float*)d_in[9];
    const float* wvc = (const float*)d_in[10];
    const float* bvc = (const float*)d_in[11];
    const float* wvp = (const float*)d_in[12];
    const float* bvp = (const float*)d_in[13];
    const float* wcp = (const float*)d_in[14];
    const float* lnw = (const float*)d_in[15];
    const float* wfc = (const float*)d_in[16];
    const float* wmp = (const float*)d_in[17];

    // ws: kbf 0.5MB | vtbf 0.5MB
    unsigned short* kbf  = (unsigned short*)d_ws;
    unsigned short* vtbf = kbf + (size_t)8 * 1024 * 32;

    kv_tcl<<<512, 256, 0, stream>>>(pkv, wkc, bkc, wkp, bkp,
                                    wvc, bvc, wvp, bvp, kbf, vtbf);
    fused_qae<<<1024, 512, 0, stream>>>(cd, wqc, bqc, wqp, bqp, kbf, vtbf,
                                        wcp, lnw, wfc, wmp, (float*)d_out);
}